// Round 6
// baseline (21.699 us; speedup 1.0000x reference)
//
#include <hip/hip_runtime.h>

// SegmentationLoss: scalar = sum_{b,l,i} g[b,l,i] * sqrt(sum_f (p[b,l,f]-g[b,l,i])^2)
// input (8,16,256,256) f32, target (8,8,256,256) f32, out: 1 f32.
// Identity: sum_f (p_f - g)^2 = s2 - 2 g s1 + NF g^2,  s1=sum_f p_f, s2=sum_f p_f^2.
//
// Round-6: SINGLE kernel, fence-free atomic reduction tree.
//   - R4's fused version died on __threadfence() x512: its acquire half
//     invalidates the XCD's L1/L2, evicting inputs under still-running blocks.
//   - Atomics are coherent at the fabric coherence point WITHOUT cache
//     maintenance. So: block partial -> relaxed agent-scope fp32 atomicAdd
//     into acc[bid&31] (32 spread 128B lines, 16-way contention each),
//     s_waitcnt vmcnt(0) (order value-add before counter-add), relaxed
//     counter bump; group-last bumps master; global-last block reads the 32
//     accumulators via relaxed atomic loads and writes out[0].
//   - Correctness chain: cnt[g]==16 => all 16 acc-adds to line g complete
//     (each block's vmcnt(0) sits between its acc-add and cnt-add);
//     master==32 => all 512 acc-adds complete => safe to read.
//   - FP add order within a line is finish-order (run-to-run wobble ~1e-2,
//     threshold 2e5). Counters re-zeroed every call by captured memset.
//
// History: R1 24.4 (atomic tail) | R2 41.8 | R3 15.7 (2-kernel) | R4 32.4
// (threadfence - reverted) | R5 16.3 (2-kernel, pure body; 2nd dispatch +
// writeback dependency ~7us of it).

#define HW   (256 * 256)
#define NF   16
#define NI   8
#define BSZ  8
#define NBLK 512
#define NGRP 32
#define GRPSZ (NBLK / NGRP)   // 16

// d_ws layout (bytes): acc lines [0,4096), cnt lines [4096,8192), master 8192.
#define ACC_OFF 0
#define CNT_OFF 4096
#define MST_OFF 8192

__global__ __launch_bounds__(256) void seg_loss_fused(const float* __restrict__ input,
                                                      const float* __restrict__ target,
                                                      float* __restrict__ out,
                                                      unsigned char* __restrict__ ws) {
    const int tid  = blockIdx.x * blockDim.x + threadIdx.x;   // 0 .. 131071
    const int loc0 = tid << 2;                                // 4 consecutive locations
    const int b    = loc0 >> 16;
    const int l    = loc0 & (HW - 1);

    const float4* ip = reinterpret_cast<const float4*>(input  + (size_t)b * NF * HW + l);
    const float4* tp = reinterpret_cast<const float4*>(target + (size_t)b * NI * HW + l);

    float4 s1 = make_float4(0.f, 0.f, 0.f, 0.f);
    float4 s2 = make_float4(0.f, 0.f, 0.f, 0.f);
#pragma unroll
    for (int f = 0; f < NF; ++f) {
        float4 p = ip[f * (HW / 4)];
        s1.x += p.x; s1.y += p.y; s1.z += p.z; s1.w += p.w;
        s2.x += p.x * p.x; s2.y += p.y * p.y; s2.z += p.z * p.z; s2.w += p.w * p.w;
    }

    float acc = 0.f;
#pragma unroll
    for (int i = 0; i < NI; ++i) {
        float4 g = tp[i * (HW / 4)];
        acc += g.x * sqrtf(fmaxf(s2.x - 2.f * g.x * s1.x + (float)NF * g.x * g.x, 0.f));
        acc += g.y * sqrtf(fmaxf(s2.y - 2.f * g.y * s1.y + (float)NF * g.y * g.y, 0.f));
        acc += g.z * sqrtf(fmaxf(s2.z - 2.f * g.z * s1.z + (float)NF * g.z * g.z, 0.f));
        acc += g.w * sqrtf(fmaxf(s2.w - 2.f * g.w * s1.w + (float)NF * g.w * g.w, 0.f));
    }

    // Wave (64-lane) reduction, then one LDS combine across the 4 waves.
#pragma unroll
    for (int off = 32; off > 0; off >>= 1)
        acc += __shfl_down(acc, off, 64);

    __shared__ float wsum[4];
    __shared__ int   amLast;
    const int lane = threadIdx.x & 63;
    const int wid  = threadIdx.x >> 6;
    if (lane == 0) wsum[wid] = acc;
    __syncthreads();

    if (threadIdx.x == 0) {
        float bsum = wsum[0] + wsum[1] + wsum[2] + wsum[3];
        const int g = blockIdx.x & (NGRP - 1);
        float*    accp = (float*)(ws + ACC_OFF + (size_t)g * 128);
        unsigned* cntp = (unsigned*)(ws + CNT_OFF + (size_t)g * 128);
        unsigned* mstp = (unsigned*)(ws + MST_OFF);

        __hip_atomic_fetch_add(accp, bsum, __ATOMIC_RELAXED, __HIP_MEMORY_SCOPE_AGENT);
        asm volatile("s_waitcnt vmcnt(0)" ::: "memory");  // acc-add complete before cnt-add

        int last = 0;
        if (__hip_atomic_fetch_add(cntp, 1u, __ATOMIC_RELAXED,
                                   __HIP_MEMORY_SCOPE_AGENT) == GRPSZ - 1) {
            if (__hip_atomic_fetch_add(mstp, 1u, __ATOMIC_RELAXED,
                                       __HIP_MEMORY_SCOPE_AGENT) == NGRP - 1)
                last = 1;
        }
        amLast = last;
    }
    __syncthreads();

    if (amLast) {
        if (threadIdx.x < 64) {          // wave 0, fully active
            float v = 0.f;
            if (threadIdx.x < 32)
                v = __hip_atomic_load((float*)(ws + ACC_OFF + (size_t)threadIdx.x * 128),
                                      __ATOMIC_RELAXED, __HIP_MEMORY_SCOPE_AGENT);
#pragma unroll
            for (int off = 32; off > 0; off >>= 1)
                v += __shfl_down(v, off, 64);
            if (threadIdx.x == 0) out[0] = v;
        }
    }
}

extern "C" void kernel_launch(void* const* d_in, const int* in_sizes, int n_in,
                              void* d_out, int out_size, void* d_ws, size_t ws_size,
                              hipStream_t stream) {
    const float* input  = (const float*)d_in[0];
    const float* target = (const float*)d_in[1];
    float* out = (float*)d_out;
    unsigned char* ws = (unsigned char*)d_ws;

    // Zero accumulators + counters every call (captured -> every replay re-zeroes).
    hipMemsetAsync(ws, 0, MST_OFF + 128, stream);

    seg_loss_fused<<<NBLK, 256, 0, stream>>>(input, target, out, ws);
}

// Round 7
// 16.586 us; speedup vs baseline: 1.3083x; 1.3083x over previous
//
#include <hip/hip_runtime.h>

// SegmentationLoss: scalar = sum_{b,l,i} g[b,l,i] * sqrt(sum_f (p[b,l,f]-g[b,l,i])^2)
// input (8,16,256,256) f32, target (8,8,256,256) f32, out: 1 f32.
// Identity: sum_f (p_f - g)^2 = s2 - 2 g s1 + NF g^2,  s1=sum_f p_f, s2=sum_f p_f^2.
//
// Round-7: two kernels, ZERO synchronization in stage1.
//   stage1: 512 blk x 256. Each thread owns one float4 group (24 independent
//           16B loads). Wave-level shfl reduce only; lane 0 writes
//           partial[globalWaveId] (2048 distinct floats -> deterministic,
//           no LDS, no __syncthreads, no atomics; waves retire independently).
//   stage2: ONE wave (64 threads): 8 coalesced float4 loads per lane over the
//           2048 partials, in-wave reduce, store out[0]. No LDS, no barriers.
//
// Lessons locked in: in-kernel coherent finishes lose to a 2nd dispatch
// (R4 threadfence 32.4, R6 relaxed-atomic tree 21.7 vs R5 16.3); same-line
// device atomics cost ~30ns each serialized (R1/R2).
// History: R1 24.4 | R2 41.8 | R3 15.7 | R4 32.4 | R5 16.3 | R6 21.7.

#define HW    (256 * 256)
#define NF    16
#define NI    8
#define BSZ   8
#define NBLK  512
#define NWAVE (NBLK * 4)   // 2048 per-wave partials

__global__ __launch_bounds__(256) void seg_loss_stage1(const float* __restrict__ input,
                                                       const float* __restrict__ target,
                                                       float* __restrict__ partial) {
    const int tid  = blockIdx.x * blockDim.x + threadIdx.x;   // 0 .. 131071
    const int loc0 = tid << 2;                                // 4 consecutive locations
    const int b    = loc0 >> 16;
    const int l    = loc0 & (HW - 1);

    const float4* ip = reinterpret_cast<const float4*>(input  + (size_t)b * NF * HW + l);
    const float4* tp = reinterpret_cast<const float4*>(target + (size_t)b * NI * HW + l);

    float4 s1 = make_float4(0.f, 0.f, 0.f, 0.f);
    float4 s2 = make_float4(0.f, 0.f, 0.f, 0.f);
#pragma unroll
    for (int f = 0; f < NF; ++f) {
        float4 p = ip[f * (HW / 4)];
        s1.x += p.x; s1.y += p.y; s1.z += p.z; s1.w += p.w;
        s2.x += p.x * p.x; s2.y += p.y * p.y; s2.z += p.z * p.z; s2.w += p.w * p.w;
    }

    float acc = 0.f;
#pragma unroll
    for (int i = 0; i < NI; ++i) {
        float4 g = tp[i * (HW / 4)];
        acc += g.x * sqrtf(fmaxf(s2.x - 2.f * g.x * s1.x + (float)NF * g.x * g.x, 0.f));
        acc += g.y * sqrtf(fmaxf(s2.y - 2.f * g.y * s1.y + (float)NF * g.y * g.y, 0.f));
        acc += g.z * sqrtf(fmaxf(s2.z - 2.f * g.z * s1.z + (float)NF * g.z * g.z, 0.f));
        acc += g.w * sqrtf(fmaxf(s2.w - 2.f * g.w * s1.w + (float)NF * g.w * g.w, 0.f));
    }

    // Wave (64-lane) reduction; lane 0 writes this wave's partial. Nothing else.
#pragma unroll
    for (int off = 32; off > 0; off >>= 1)
        acc += __shfl_down(acc, off, 64);

    const int lane = threadIdx.x & 63;
    const int gwid = (blockIdx.x << 2) | (threadIdx.x >> 6);   // 0 .. 2047
    if (lane == 0) partial[gwid] = acc;
}

__global__ __launch_bounds__(64) void seg_loss_stage2(const float* __restrict__ partial,
                                                      float* __restrict__ out) {
    const float4* p4 = reinterpret_cast<const float4*>(partial);  // 512 float4
    float s = 0.f;
#pragma unroll
    for (int k = 0; k < 8; ++k) {                 // lane i reads p4[i + 64k]
        float4 v = p4[threadIdx.x + (k << 6)];
        s += v.x + v.y + v.z + v.w;
    }
#pragma unroll
    for (int off = 32; off > 0; off >>= 1)
        s += __shfl_down(s, off, 64);
    if (threadIdx.x == 0) out[0] = s;
}

extern "C" void kernel_launch(void* const* d_in, const int* in_sizes, int n_in,
                              void* d_out, int out_size, void* d_ws, size_t ws_size,
                              hipStream_t stream) {
    const float* input  = (const float*)d_in[0];
    const float* target = (const float*)d_in[1];
    float* out     = (float*)d_out;
    float* partial = (float*)d_ws;   // 2048 floats = 8 KB scratch

    seg_loss_stage1<<<NBLK, 256, 0, stream>>>(input, target, partial);
    seg_loss_stage2<<<1, 64, 0, stream>>>(partial, out);
}

// Round 8
// 16.328 us; speedup vs baseline: 1.3290x; 1.0158x over previous
//
#include <hip/hip_runtime.h>

// SegmentationLoss: scalar = sum_{b,l,i} g[b,l,i] * sqrt(sum_f (p[b,l,f]-g[b,l,i])^2)
// input (8,16,256,256) f32, target (8,8,256,256) f32, out: 1 f32.
// Identity: sum_f (p_f - g)^2 = s2 - 2 g s1 + NF g^2,  s1=sum_f p_f, s2=sum_f p_f^2.
//
// Round-8: occupancy test. float2 granularity -> 262144 threads, 4096 waves
// = 16 waves/CU (2x round 7). Still fully coalesced (512B per wave-load).
// Zero-sync stage1 (per-wave partial), one-wave stage2. No atomics anywhere.
//
// Locked-in lessons: in-kernel coherent finishes lose to a 2nd dispatch
// (R4 32.4 threadfence, R6 21.7 atomic-tree vs R5 16.3); same-line atomics
// ~20-30ns each serialized (R1); stage1 sync structure irrelevant (R3=R5=R7).
// History: R1 24.4 | R2 41.8 | R3 15.7 | R4 32.4 | R5 16.3 | R6 21.7 | R7 16.6.

#define HW    (256 * 256)
#define NF    16
#define NI    8
#define BSZ   8
#define NTHR  (BSZ * HW / 2)    // 262144 threads, one float2 each
#define NBLK  (NTHR / 256)      // 1024 blocks
#define NWAVE (NTHR / 64)       // 4096 wave partials

__global__ __launch_bounds__(256) void seg_loss_stage1(const float* __restrict__ input,
                                                       const float* __restrict__ target,
                                                       float* __restrict__ partial) {
    const int tid  = blockIdx.x * blockDim.x + threadIdx.x;   // 0 .. 262143
    const int loc0 = tid << 1;                                // 2 consecutive locations
    const int b    = loc0 >> 16;
    const int l    = loc0 & (HW - 1);

    const float2* ip = reinterpret_cast<const float2*>(input  + (size_t)b * NF * HW + l);
    const float2* tp = reinterpret_cast<const float2*>(target + (size_t)b * NI * HW + l);

    float2 s1 = make_float2(0.f, 0.f);
    float2 s2 = make_float2(0.f, 0.f);
#pragma unroll
    for (int f = 0; f < NF; ++f) {
        float2 p = ip[f * (HW / 2)];
        s1.x += p.x; s1.y += p.y;
        s2.x += p.x * p.x; s2.y += p.y * p.y;
    }

    float acc = 0.f;
#pragma unroll
    for (int i = 0; i < NI; ++i) {
        float2 g = tp[i * (HW / 2)];
        acc += g.x * sqrtf(fmaxf(s2.x - 2.f * g.x * s1.x + (float)NF * g.x * g.x, 0.f));
        acc += g.y * sqrtf(fmaxf(s2.y - 2.f * g.y * s1.y + (float)NF * g.y * g.y, 0.f));
    }

    // Wave reduction; lane 0 writes this wave's partial. No LDS/barriers/atomics.
#pragma unroll
    for (int off = 32; off > 0; off >>= 1)
        acc += __shfl_down(acc, off, 64);

    const int lane = threadIdx.x & 63;
    const int gwid = (blockIdx.x << 2) | (threadIdx.x >> 6);   // 0 .. 4095
    if (lane == 0) partial[gwid] = acc;
}

__global__ __launch_bounds__(64) void seg_loss_stage2(const float* __restrict__ partial,
                                                      float* __restrict__ out) {
    const float4* p4 = reinterpret_cast<const float4*>(partial);  // 1024 float4
    float s = 0.f;
#pragma unroll
    for (int k = 0; k < 16; ++k) {                // lane i reads p4[i + 64k]
        float4 v = p4[threadIdx.x + (k << 6)];
        s += v.x + v.y + v.z + v.w;
    }
#pragma unroll
    for (int off = 32; off > 0; off >>= 1)
        s += __shfl_down(s, off, 64);
    if (threadIdx.x == 0) out[0] = s;
}

extern "C" void kernel_launch(void* const* d_in, const int* in_sizes, int n_in,
                              void* d_out, int out_size, void* d_ws, size_t ws_size,
                              hipStream_t stream) {
    const float* input  = (const float*)d_in[0];
    const float* target = (const float*)d_in[1];
    float* out     = (float*)d_out;
    float* partial = (float*)d_ws;   // 4096 floats = 16 KB scratch

    seg_loss_stage1<<<NBLK, 256, 0, stream>>>(input, target, partial);
    seg_loss_stage2<<<1, 64, 0, stream>>>(partial, out);
}

// Round 10
// 14.652 us; speedup vs baseline: 1.4810x; 1.1144x over previous
//
#include <hip/hip_runtime.h>

// SegmentationLoss: scalar = sum_{b,l,i} g[b,l,i] * sqrt(sum_f (p[b,l,f]-g[b,l,i])^2)
// input (8,16,256,256) f32, target (8,8,256,256) f32, out: 1 f32.
// Identity: sum_f (p_f - g)^2 = s2 - 2 g s1 + NF g^2,  s1=sum_f p_f, s2=sum_f p_f^2.
//
// Round-10: R9 retry (compile fix). __builtin_nontemporal_load needs a native
// clang vector type, not HIP_vector_type -> use ext_vector_type(4) float.
// One variable vs R7: all stage1 global reads use the streaming/no-allocate
// cache policy (inputs are stream-once, evicted by harness fills each replay).
//
// Locked-in lessons: in-kernel coherent finishes lose to a 2nd dispatch
// (R4 32.4, R6 21.7 vs R5 16.3); same-line atomics ~30ns serialized (R1/R2);
// stage1 sync structure irrelevant (R3=R5=R7); occupancy 8 vs 16 waves/CU
// irrelevant (R7=R8).
// History: R1 24.4 | R2 41.8 | R3 15.7 | R4 32.4 | R5 16.3 | R6 21.7
//        | R7 16.6 | R8 16.3 | R9 compile-fail.

#define HW    (256 * 256)
#define NF    16
#define NI    8
#define BSZ   8
#define NBLK  512

typedef float f32x4 __attribute__((ext_vector_type(4)));

__global__ __launch_bounds__(256) void seg_loss_stage1(const float* __restrict__ input,
                                                       const float* __restrict__ target,
                                                       float* __restrict__ partial) {
    const int tid  = blockIdx.x * blockDim.x + threadIdx.x;   // 0 .. 131071
    const int loc0 = tid << 2;                                // 4 consecutive locations
    const int b    = loc0 >> 16;
    const int l    = loc0 & (HW - 1);

    const f32x4* ip = reinterpret_cast<const f32x4*>(input  + (size_t)b * NF * HW + l);
    const f32x4* tp = reinterpret_cast<const f32x4*>(target + (size_t)b * NI * HW + l);

    f32x4 s1 = (f32x4)(0.f);
    f32x4 s2 = (f32x4)(0.f);
#pragma unroll
    for (int f = 0; f < NF; ++f) {
        f32x4 p = __builtin_nontemporal_load(&ip[f * (HW / 4)]);
        s1 += p;
        s2 += p * p;
    }

    float acc = 0.f;
#pragma unroll
    for (int i = 0; i < NI; ++i) {
        f32x4 g = __builtin_nontemporal_load(&tp[i * (HW / 4)]);
        f32x4 q = s2 - 2.f * g * s1 + (float)NF * g * g;
        acc += g.x * sqrtf(fmaxf(q.x, 0.f));
        acc += g.y * sqrtf(fmaxf(q.y, 0.f));
        acc += g.z * sqrtf(fmaxf(q.z, 0.f));
        acc += g.w * sqrtf(fmaxf(q.w, 0.f));
    }

    // Wave reduction; lane 0 writes this wave's partial. No LDS/barriers/atomics.
#pragma unroll
    for (int off = 32; off > 0; off >>= 1)
        acc += __shfl_down(acc, off, 64);

    const int lane = threadIdx.x & 63;
    const int gwid = (blockIdx.x << 2) | (threadIdx.x >> 6);   // 0 .. 2047
    if (lane == 0) partial[gwid] = acc;
}

__global__ __launch_bounds__(64) void seg_loss_stage2(const float* __restrict__ partial,
                                                      float* __restrict__ out) {
    const f32x4* p4 = reinterpret_cast<const f32x4*>(partial);  // 512 f32x4
    float s = 0.f;
#pragma unroll
    for (int k = 0; k < 8; ++k) {                 // lane i reads p4[i + 64k]
        f32x4 v = p4[threadIdx.x + (k << 6)];
        s += v.x + v.y + v.z + v.w;
    }
#pragma unroll
    for (int off = 32; off > 0; off >>= 1)
        s += __shfl_down(s, off, 64);
    if (threadIdx.x == 0) out[0] = s;
}

extern "C" void kernel_launch(void* const* d_in, const int* in_sizes, int n_in,
                              void* d_out, int out_size, void* d_ws, size_t ws_size,
                              hipStream_t stream) {
    const float* input  = (const float*)d_in[0];
    const float* target = (const float*)d_in[1];
    float* out     = (float*)d_out;
    float* partial = (float*)d_ws;   // 2048 floats = 8 KB scratch

    seg_loss_stage1<<<NBLK, 256, 0, stream>>>(input, target, partial);
    seg_loss_stage2<<<1, 64, 0, stream>>>(partial, out);
}

// Round 11
// 14.586 us; speedup vs baseline: 1.4876x; 1.0045x over previous
//
#include <hip/hip_runtime.h>

// SegmentationLoss: scalar = sum_{b,l,i} g[b,l,i] * sqrt(sum_f (p[b,l,f]-g[b,l,i])^2)
// input (8,16,256,256) f32, target (8,8,256,256) f32, out: 1 f32.
// Identity: sum_f (p_f - g)^2 = s2 - 2 g s1 + NF g^2,  s1=sum_f p_f, s2=sum_f p_f^2.
//
// Round-11: R10 (NT loads, best @ 14.65us) + float2 granularity -> 4096 waves
// = 16 waves/CU. Re-test of occupancy UNDER the NT policy (R8's occupancy
// null was with caching loads; NT pays full HBM latency -> request-level
// parallelism may now be the limiter).
//
// Locked-in lessons: NT no-allocate loads on stream-once inputs: -1.9us (R10);
// in-kernel coherent finishes lose to a 2nd dispatch (R4 32.4, R6 21.7 vs
// R5 16.3); same-line atomics ~30ns serialized (R1/R2); stage1 sync structure
// irrelevant (R3=R5=R7); occupancy irrelevant under CACHING loads (R7=R8).
// History: R1 24.4 | R2 41.8 | R3 15.7 | R4 32.4 | R5 16.3 | R6 21.7
//        | R7 16.6 | R8 16.3 | R9 cfail | R10 14.65.

#define HW    (256 * 256)
#define NF    16
#define NI    8
#define BSZ   8
#define NTHR  (BSZ * HW / 2)    // 262144 threads, one float2 each
#define NBLK  (NTHR / 256)      // 1024 blocks

typedef float f32x2 __attribute__((ext_vector_type(2)));
typedef float f32x4 __attribute__((ext_vector_type(4)));

__global__ __launch_bounds__(256) void seg_loss_stage1(const float* __restrict__ input,
                                                       const float* __restrict__ target,
                                                       float* __restrict__ partial) {
    const int tid  = blockIdx.x * blockDim.x + threadIdx.x;   // 0 .. 262143
    const int loc0 = tid << 1;                                // 2 consecutive locations
    const int b    = loc0 >> 16;
    const int l    = loc0 & (HW - 1);

    const f32x2* ip = reinterpret_cast<const f32x2*>(input  + (size_t)b * NF * HW + l);
    const f32x2* tp = reinterpret_cast<const f32x2*>(target + (size_t)b * NI * HW + l);

    f32x2 s1 = (f32x2)(0.f);
    f32x2 s2 = (f32x2)(0.f);
#pragma unroll
    for (int f = 0; f < NF; ++f) {
        f32x2 p = __builtin_nontemporal_load(&ip[f * (HW / 2)]);
        s1 += p;
        s2 += p * p;
    }

    float acc = 0.f;
#pragma unroll
    for (int i = 0; i < NI; ++i) {
        f32x2 g = __builtin_nontemporal_load(&tp[i * (HW / 2)]);
        f32x2 q = s2 - 2.f * g * s1 + (float)NF * g * g;
        acc += g.x * sqrtf(fmaxf(q.x, 0.f));
        acc += g.y * sqrtf(fmaxf(q.y, 0.f));
    }

    // Wave reduction; lane 0 writes this wave's partial. No LDS/barriers/atomics.
#pragma unroll
    for (int off = 32; off > 0; off >>= 1)
        acc += __shfl_down(acc, off, 64);

    const int lane = threadIdx.x & 63;
    const int gwid = (blockIdx.x << 2) | (threadIdx.x >> 6);   // 0 .. 4095
    if (lane == 0) partial[gwid] = acc;
}

__global__ __launch_bounds__(64) void seg_loss_stage2(const float* __restrict__ partial,
                                                      float* __restrict__ out) {
    const f32x4* p4 = reinterpret_cast<const f32x4*>(partial);  // 1024 f32x4
    float s = 0.f;
#pragma unroll
    for (int k = 0; k < 16; ++k) {                // lane i reads p4[i + 64k]
        f32x4 v = p4[threadIdx.x + (k << 6)];
        s += v.x + v.y + v.z + v.w;
    }
#pragma unroll
    for (int off = 32; off > 0; off >>= 1)
        s += __shfl_down(s, off, 64);
    if (threadIdx.x == 0) out[0] = s;
}

extern "C" void kernel_launch(void* const* d_in, const int* in_sizes, int n_in,
                              void* d_out, int out_size, void* d_ws, size_t ws_size,
                              hipStream_t stream) {
    const float* input  = (const float*)d_in[0];
    const float* target = (const float*)d_in[1];
    float* out     = (float*)d_out;
    float* partial = (float*)d_ws;   // 4096 floats = 16 KB scratch

    seg_loss_stage1<<<NBLK, 256, 0, stream>>>(input, target, partial);
    seg_loss_stage2<<<1, 64, 0, stream>>>(partial, out);
}